// Round 5
// baseline (487.629 us; speedup 1.0000x reference)
//
#include <hip/hip_runtime.h>

// Decoder_33208687133135 — fused Koopman decoder, MI355X (gfx950).
// Diagonal-only -> layer4 is a per-row dot. ~292 GFLOP, f16 MFMA
// (absmax 0.0625 vs thr 0.2425, stable R1-R4).
//
// R4 post-mortem: 351 us; real MFMA issue only ~10% of cycles; weight
// stream 18.9 MB/CU has a ~140 us L2-BW floor in this decomposition
// (acc=64 AGPR locks M=64/WG; N=512 must stay intra-WG). Gap above floor =
// depth-1 prefetch (78 cyc lookahead vs ~200 cyc L2 latency) + barrier
// lockstep + __syncthreads draining vmcnt(0) each layer (m97 stall).
// R5: (a) repack weights into per-wave-contiguous nt-pair entries; whole
// kernel's 136-entry load stream is one predetermined sequence via an LDS
// offset table; (b) register ring depth 4 (32 VGPR), refilled 1 entry per
// 8 MFMAs, loads cross layer/net boundaries; (c) barriers = s_waitcnt
// lgkmcnt(0)+s_barrier only (ring loads stay in flight across barriers —
// AITER-style fine-grained vmcnt, never 0); (d) coalesced LDS-transpose
// pack kernel (R4's scatter-read pack cost ~80 us of the total).

typedef _Float16 f16;
typedef _Float16 f16x8 __attribute__((ext_vector_type(8)));
typedef float f32x4 __attribute__((ext_vector_type(4)));

#define WPACK_PER_NET 589824
#define OFF_W1 0
#define OFF_W2 32768
#define OFF_W3 294912
#define OFF_W4T 557056
#define WPACK_BYTES (2u * WPACK_PER_NET * sizeof(f16))  // 2.36 MB

// Barrier with LDS-visibility only: does NOT drain vmcnt, so in-flight
// weight prefetches survive layer boundaries. Safe: ring loads target
// VGPRs (compiler inserts per-use vmcnt waits); barrier only needs ds
// ordering (lgkmcnt).
__device__ __forceinline__ void lds_barrier() {
  asm volatile("s_waitcnt lgkmcnt(0)\n\ts_barrier" ::: "memory");
}

// ---------------- pack layout v2 (per-wave contiguous entries) ----------
// Layer block (NS slices): off = kk*16384 + w*2048 + p*1024 + nt2*512
//                                + lane*8 + j   (f16 units)
// holding W[k][n] with n = w*64 + (p*2+nt2)*16 + (lane&15),
//                     k = kk*32 + (lane>>4)*8 + j.
// Entry (kk,p) = wave's 2 B-frags: 16B @ +0 and 16B @ +1024 bytes.
// W4T block unchanged: [i][k] transposed, i*512+k.
__global__ __launch_bounds__(512) void pack_weights2(
    const float* __restrict__ sW1, const float* __restrict__ sW2,
    const float* __restrict__ sW3, const float* __restrict__ sW4,
    const float* __restrict__ tW1, const float* __restrict__ tW2,
    const float* __restrict__ tW3, const float* __restrict__ tW4,
    f16* __restrict__ dst) {
  __shared__ f16 sb[32768];  // 64 KB
  const int w = blockIdx.x, t = threadIdx.x;
  if (w < 68) {  // one WG per 32-k slice of W1/W2/W3
    int net = w >= 34;
    int s = w - net * 34;
    int l = (s < 2) ? 0 : (s < 18 ? 1 : 2);
    int kk = s - (l == 0 ? 0 : (l == 1 ? 2 : 18));
    const float* W = l == 0 ? (net ? tW1 : sW1)
                            : (l == 1 ? (net ? tW2 : sW2) : (net ? tW3 : sW3));
    int lb = l == 0 ? OFF_W1 : (l == 1 ? OFF_W2 : OFF_W3);
    // coalesced fp32 read -> LDS [kloc][n]
#pragma unroll
    for (int i = 0; i < 32; i++) sb[i * 512 + t] = (f16)W[(kk * 32 + i) * 512 + t];
    __syncthreads();
    f16* db = dst + net * WPACK_PER_NET + lb + kk * 16384;
    // coalesced f16 write, scattered LDS read
#pragma unroll
    for (int q = 0; q < 32; q++) {
      int flat = q * 512 + t;
      int w_ = flat >> 11, r2 = flat & 2047;
      int p = r2 >> 10, nt2 = (r2 >> 9) & 1, ln = (r2 >> 3) & 63, j = r2 & 7;
      int n = w_ * 64 + (p * 2 + nt2) * 16 + (ln & 15);
      int kloc = (ln >> 4) * 8 + j;
      db[flat] = sb[kloc * 512 + n];
    }
  } else {  // W4 transpose (one WG per net)
    int net = w - 68;
    const float* W4 = net ? tW4 : sW4;
#pragma unroll
    for (int q = 0; q < 64; q++) {
      int u = q * 512 + t;
      sb[u] = (f16)W4[u];  // u = k*64+i, coalesced
    }
    __syncthreads();
    f16* db = dst + net * WPACK_PER_NET + OFF_W4T;
#pragma unroll
    for (int q = 0; q < 64; q++) {
      int d = q * 512 + t;  // d = i*512+k
      db[d] = sb[(d & 511) * 64 + (d >> 9)];
    }
  }
}

// A-fragment order index for activation element (m,k).
__device__ __forceinline__ int aidx(int m, int k) {
  return (((k >> 5) * 4 + (m >> 4)) * 64 + (m & 15) + ((k >> 3) & 3) * 16) * 8 + (k & 7);
}

// tanh(x) = 1 - 2/(exp(2x)+1); 6 VALU inst, correct saturation.
__device__ __forceinline__ float fast_tanh(float x) {
  float e = __expf(x + x);
  return fmaf(-2.0f, __builtin_amdgcn_rcpf(e + 1.0f), 1.0f);
}

// One MLP layer, ring-pipelined: Hout(64x512) = tanh(Asrc(64xK)@W + bias).
// Entry stream index = estart + 2*kk + p; refills entry +4 ahead (may
// belong to the next layer/net — addresses from the LDS eoff table).
template <int NS>
__device__ __forceinline__ void layer_ring(
    const char* __restrict__ wb, const unsigned int* eoff, int estart,
    f16x8 (&ring)[4][2], const float* __restrict__ bias,
    const f16* Asrc, f16* Hout, int wave, int lane, int sbase, int laneoff) {
  f32x4 acc[4][4];
#pragma unroll
  for (int nt = 0; nt < 4; nt++) {
    float bv = bias[wave * 64 + nt * 16 + (lane & 15)];
#pragma unroll
    for (int mt = 0; mt < 4; mt++) acc[mt][nt] = f32x4{bv, bv, bv, bv};
  }
#pragma unroll
  for (int kk = 0; kk < NS; kk++) {
    const f16* ab = Asrc + kk * 2048 + lane * 8;
    f16x8 a[4];
#pragma unroll
    for (int mt = 0; mt < 4; mt++) a[mt] = *(const f16x8*)(ab + mt * 512);
#pragma unroll
    for (int p = 0; p < 2; p++) {
      const int slot = (2 * kk + p) & 3;  // layer blocks are multiples of 4
      f16x8 b0 = ring[slot][0], b1 = ring[slot][1];
      {  // refill: entry estart+2kk+p+4 of the global stream
        const char* gp = wb + eoff[estart + 2 * kk + p + 4] + laneoff;
        ring[slot][0] = *(const f16x8*)gp;
        ring[slot][1] = *(const f16x8*)(gp + 1024);
      }
#pragma unroll
      for (int mt = 0; mt < 4; mt++) {
        acc[mt][2 * p] = __builtin_amdgcn_mfma_f32_16x16x32_f16(
            a[mt], b0, acc[mt][2 * p], 0, 0, 0);
        acc[mt][2 * p + 1] = __builtin_amdgcn_mfma_f32_16x16x32_f16(
            a[mt], b1, acc[mt][2 * p + 1], 0, 0, 0);
      }
    }
  }
  lds_barrier();  // all waves done reading Asrc (aliases Hout); vmcnt live
  // C/D (m89/m91): col=wave*64+nt*16+(lane&15), row=mt*16+(lane>>4)*4+r.
  // Scatter = sbase(lane) + const(mt,nt,r)  [verified R4].
  f16* hb = Hout + sbase;
#pragma unroll
  for (int mt = 0; mt < 4; mt++)
#pragma unroll
    for (int nt = 0; nt < 4; nt++)
#pragma unroll
      for (int r = 0; r < 4; r++)
        hb[(nt >> 1) * 2048 + mt * 512 + (nt & 1) * 256 + r * 8] =
            (f16)fast_tanh(acc[mt][nt][r]);
  lds_barrier();
}

__global__ __launch_bounds__(512, 4) void decoder_ring(
    const float* __restrict__ x, const float* __restrict__ koop,
    const f16* __restrict__ wpack,
    const float* __restrict__ sb1, const float* __restrict__ sb2,
    const float* __restrict__ sb3, const float* __restrict__ sb4,
    const float* __restrict__ tb1, const float* __restrict__ tb2,
    const float* __restrict__ tb3, const float* __restrict__ tb4,
    float* __restrict__ out) {
  __shared__ __align__(16) f16 ZA[4096];   // z tile, A-frag order (8 KB)
  __shared__ __align__(16) f16 HA[32768];  // activations (64 KB)
  __shared__ unsigned int eoff[144];       // entry base byte-offsets
  __shared__ float redBuf[2][64];
  // ~73 KB -> 2 WG/CU

  const int b = blockIdx.x;
  const int t = threadIdx.x;
  const int wave = t >> 6, lane = t & 63;
  const int sbase =
      wave * 4096 + (lane >> 4) * 32 + ((lane & 15) >> 3) * 128 + (lane & 7);
  const int laneoff = wave * 4096 + lane * 16;  // bytes within entry

  // Entry offset table: 136 real entries (2 nets x (4+32+32)), pad to 144.
  if (t < 144) {
    unsigned int off = 0;
    if (t < 136) {
      int net = t >= 68;
      int r = t - net * 68;
      int l = (r < 4) ? 0 : (r < 36 ? 1 : 2);
      int rr = r - (l == 0 ? 0 : (l == 1 ? 4 : 36));
      int lb = (l == 0) ? OFF_W1 : (l == 1 ? OFF_W2 : OFF_W3);
      off = (unsigned int)(net * WPACK_PER_NET + lb + (rr >> 1) * 16384 +
                           (rr & 1) * 1024) * 2u;
    }
    eoff[t] = off;
  }

  // Stage z = koopman[b]^T as f16 A-fragments.
  const float* kb = koop + b * 4096;
#pragma unroll
  for (int i = 0; i < 8; i++) {
    int flat = t + 512 * i;
    ZA[aidx(flat & 63, flat >> 6)] = (f16)kb[flat];
  }
  __syncthreads();  // orders eoff + ZA (full drain once is fine)

  // Prime the ring with entries 0..3.
  const char* wb = (const char*)wpack;
  f16x8 ring[4][2];
#pragma unroll
  for (int s = 0; s < 4; s++) {
    const char* gp = wb + eoff[s] + laneoff;
    ring[s][0] = *(const f16x8*)gp;
    ring[s][1] = *(const f16x8*)(gp + 1024);
  }

#pragma unroll 1  // rolled: keeps code ~13 KB (I-cache)
  for (int net = 0; net < 2; net++) {
    const float* b1 = net ? tb1 : sb1;
    const float* b2 = net ? tb2 : sb2;
    const float* b3 = net ? tb3 : sb3;
    const float* b4 = net ? tb4 : sb4;
    const int e0 = net * 68;
    layer_ring<2>(wb, eoff, e0, ring, b1, ZA, HA, wave, lane, sbase, laneoff);
    layer_ring<16>(wb, eoff, e0 + 4, ring, b2, HA, HA, wave, lane, sbase, laneoff);
    layer_ring<16>(wb, eoff, e0 + 36, ring, b3, HA, HA, wave, lane, sbase, laneoff);

    // Diagonal epilogue: ds[i] = H3[i,:] . W4T[i,:] + b4[i].
    const f16* w4t = wpack + net * WPACK_PER_NET + OFF_W4T;
    int i = t >> 3, sub = t & 7;
    float p = 0.f;
#pragma unroll
    for (int q = 0; q < 8; q++) {
      int k0 = sub * 64 + q * 8;
      f16x8 hv = *(const f16x8*)&HA[aidx(i, k0)];
      f16x8 wv = *(const f16x8*)&w4t[i * 512 + k0];
#pragma unroll
      for (int j = 0; j < 8; j++) p += (float)hv[j] * (float)wv[j];
    }
    p += __shfl_down(p, 4, 8);
    p += __shfl_down(p, 2, 8);
    p += __shfl_down(p, 1, 8);
    if (sub == 0) redBuf[net][i] = p + b4[i];
    lds_barrier();
  }

  if (t < 64) {
    out[b * 64 + t] = (x[b * 64 + t] - redBuf[1][t]) * __expf(-redBuf[0][t]);
  }
}

// ---------------- DIRECT fallback (no workspace) — R4 code ---------------
__device__ __forceinline__ void load_b_direct(const float* __restrict__ Wraw,
                                              int kk, int wave, int lane,
                                              f16x8* bdst) {
  int n0 = wave * 64 + (lane & 15);
  int kb = kk * 32 + (lane >> 4) * 8;
#pragma unroll
  for (int nt = 0; nt < 4; nt++) {
    f16x8 v;
#pragma unroll
    for (int j = 0; j < 8; j++) v[j] = (f16)Wraw[(kb + j) * 512 + n0 + nt * 16];
    bdst[nt] = v;
  }
}

template <int NS>
__device__ __forceinline__ void mlp_layer_direct(
    const float* __restrict__ Wraw, const float* __restrict__ bias,
    const f16* Asrc, f16* Hout, int wave, int lane, int sbase) {
  f32x4 acc[4][4];
#pragma unroll
  for (int nt = 0; nt < 4; nt++) {
    float bv = bias[wave * 64 + nt * 16 + (lane & 15)];
#pragma unroll
    for (int mt = 0; mt < 4; mt++) acc[mt][nt] = f32x4{bv, bv, bv, bv};
  }
  f16x8 bb[2][4];
  load_b_direct(Wraw, 0, wave, lane, bb[0]);
#pragma unroll
  for (int kk = 0; kk < NS; kk++) {
    if (kk + 1 < NS) load_b_direct(Wraw, kk + 1, wave, lane, bb[(kk + 1) & 1]);
    const f16* ab = Asrc + kk * 2048 + lane * 8;
    f16x8 a[4];
#pragma unroll
    for (int mt = 0; mt < 4; mt++) a[mt] = *(const f16x8*)(ab + mt * 512);
#pragma unroll
    for (int mt = 0; mt < 4; mt++)
#pragma unroll
      for (int nt = 0; nt < 4; nt++)
        acc[mt][nt] = __builtin_amdgcn_mfma_f32_16x16x32_f16(a[mt], bb[kk & 1][nt],
                                                             acc[mt][nt], 0, 0, 0);
  }
  __syncthreads();
  f16* hb = Hout + sbase;
#pragma unroll
  for (int mt = 0; mt < 4; mt++)
#pragma unroll
    for (int nt = 0; nt < 4; nt++)
#pragma unroll
      for (int r = 0; r < 4; r++)
        hb[(nt >> 1) * 2048 + mt * 512 + (nt & 1) * 256 + r * 8] =
            (f16)fast_tanh(acc[mt][nt][r]);
  __syncthreads();
}

__global__ __launch_bounds__(512, 4) void decoder_direct(
    const float* __restrict__ x, const float* __restrict__ koop,
    const float* __restrict__ sW1, const float* __restrict__ sW2,
    const float* __restrict__ sW3, const float* __restrict__ sW4,
    const float* __restrict__ tW1, const float* __restrict__ tW2,
    const float* __restrict__ tW3, const float* __restrict__ tW4,
    const float* __restrict__ sb1, const float* __restrict__ sb2,
    const float* __restrict__ sb3, const float* __restrict__ sb4,
    const float* __restrict__ tb1, const float* __restrict__ tb2,
    const float* __restrict__ tb3, const float* __restrict__ tb4,
    float* __restrict__ out) {
  __shared__ __align__(16) f16 ZA[4096];
  __shared__ __align__(16) f16 HA[32768];
  __shared__ float redBuf[2][64];
  const int b = blockIdx.x;
  const int t = threadIdx.x;
  const int wave = t >> 6, lane = t & 63;
  const int sbase =
      wave * 4096 + (lane >> 4) * 32 + ((lane & 15) >> 3) * 128 + (lane & 7);
  const float* kb = koop + b * 4096;
#pragma unroll
  for (int i = 0; i < 8; i++) {
    int flat = t + 512 * i;
    ZA[aidx(flat & 63, flat >> 6)] = (f16)kb[flat];
  }
  __syncthreads();
  for (int net = 0; net < 2; net++) {
    const float* W1 = net ? tW1 : sW1;
    const float* W2 = net ? tW2 : sW2;
    const float* W3 = net ? tW3 : sW3;
    const float* W4 = net ? tW4 : sW4;
    const float* b1 = net ? tb1 : sb1;
    const float* b2 = net ? tb2 : sb2;
    const float* b3 = net ? tb3 : sb3;
    const float* b4 = net ? tb4 : sb4;
    mlp_layer_direct<2>(W1, b1, ZA, HA, wave, lane, sbase);
    mlp_layer_direct<16>(W2, b2, HA, HA, wave, lane, sbase);
    mlp_layer_direct<16>(W3, b3, HA, HA, wave, lane, sbase);
    int i = t >> 3, sub = t & 7;
    float p = 0.f;
#pragma unroll
    for (int q = 0; q < 8; q++) {
      int k0 = sub * 64 + q * 8;
      f16x8 hv = *(const f16x8*)&HA[aidx(i, k0)];
#pragma unroll
      for (int j = 0; j < 8; j++) p += (float)hv[j] * W4[(k0 + j) * 64 + i];
    }
    p += __shfl_down(p, 4, 8);
    p += __shfl_down(p, 2, 8);
    p += __shfl_down(p, 1, 8);
    if (sub == 0) redBuf[net][i] = p + b4[i];
    __syncthreads();
  }
  if (t < 64) {
    out[b * 64 + t] = (x[b * 64 + t] - redBuf[1][t]) * __expf(-redBuf[0][t]);
  }
}

extern "C" void kernel_launch(void* const* d_in, const int* in_sizes, int n_in,
                              void* d_out, int out_size, void* d_ws, size_t ws_size,
                              hipStream_t stream) {
  const float* x    = (const float*)d_in[0];
  const float* koop = (const float*)d_in[1];
  const float* sW1 = (const float*)d_in[2];  const float* sb1 = (const float*)d_in[3];
  const float* sW2 = (const float*)d_in[4];  const float* sb2 = (const float*)d_in[5];
  const float* sW3 = (const float*)d_in[6];  const float* sb3 = (const float*)d_in[7];
  const float* sW4 = (const float*)d_in[8];  const float* sb4 = (const float*)d_in[9];
  const float* tW1 = (const float*)d_in[10]; const float* tb1 = (const float*)d_in[11];
  const float* tW2 = (const float*)d_in[12]; const float* tb2 = (const float*)d_in[13];
  const float* tW3 = (const float*)d_in[14]; const float* tb3 = (const float*)d_in[15];
  const float* tW4 = (const float*)d_in[16]; const float* tb4 = (const float*)d_in[17];
  float* out = (float*)d_out;

  // Launch-invariant branch (ws_size constant across calls) -> graph-safe.
  // NEVER write past ws_size (R1 lesson).
  if (ws_size >= (size_t)WPACK_BYTES) {
    f16* wpack = (f16*)d_ws;
    pack_weights2<<<70, 512, 0, stream>>>(sW1, sW2, sW3, sW4, tW1, tW2, tW3, tW4,
                                          wpack);
    decoder_ring<<<2048, 512, 0, stream>>>(x, koop, wpack,
                                           sb1, sb2, sb3, sb4,
                                           tb1, tb2, tb3, tb4, out);
  } else {
    decoder_direct<<<2048, 512, 0, stream>>>(
        x, koop, sW1, sW2, sW3, sW4, tW1, tW2, tW3, tW4,
        sb1, sb2, sb3, sb4, tb1, tb2, tb3, tb4, out);
  }
}

// Round 6
// 439.864 us; speedup vs baseline: 1.1086x; 1.1086x over previous
//
#include <hip/hip_runtime.h>

// Decoder_33208687133135 — fused Koopman decoder, MI355X (gfx950).
// Diagonal-only -> layer4 is a per-row dot. ~292 GFLOP, f16 MFMA
// (absmax 0.0625 vs thr 0.2425, stable R1-R5).
//
// R5 post-mortem: ring+eoff REGRESSED (351->408): 64 arch VGPRs is the hard
// budget (128 unified @ 4 waves/SIMD minus 64 acc AGPRs); ring 32 + a 16 +
// eoff/addr overhead spilled harder (WRITE_SIZE 57MB vs 0.5MB real), and
// eoff ds_read serialized refills. R6: R4's proven depth-1 double buffer
// (bb[2][4]=32 regs) + R5's pack layout so each slice's 4 B-frags are ONE
// base address + immediate offsets {0,1024,2048,3072}, next slice = +32768;
// a-frags loaded one-per-mt (4 regs). Est. arch usage ~50 < 64 -> no spill.
// Non-draining lds_barrier kept (weight loads stay in flight across layer
// boundaries; LDS-visibility via lgkmcnt(0) only).

typedef _Float16 f16;
typedef _Float16 f16x8 __attribute__((ext_vector_type(8)));
typedef float f32x4 __attribute__((ext_vector_type(4)));

#define WPACK_PER_NET 589824
#define OFF_W1 0
#define OFF_W2 32768
#define OFF_W3 294912
#define OFF_W4T 557056
#define WPACK_BYTES (2u * WPACK_PER_NET * sizeof(f16))  // 2.36 MB

// Barrier with LDS-visibility only (no vmcnt drain): in-flight global
// weight prefetches survive the barrier; compiler inserts per-use vmcnt
// waits for the VGPR-targeted loads. "memory" clobber = compiler fence.
__device__ __forceinline__ void lds_barrier() {
  asm volatile("s_waitcnt lgkmcnt(0)\n\ts_barrier" ::: "memory");
}

// ---------------- pack: fp32 -> f16, per-wave-contiguous entries ---------
// Layer block, f16 flat index: f = kk*16384 + w*2048 + nt*512 + ln*8 + j
// holding W[k][n], n = w*64 + nt*16 + (ln&15), k = kk*32 + (ln>>4)*8 + j.
// Decoder: wave w, slice kk reads 4 x 16B at byte base
//   (layer)*2 + kk*32768 + w*4096 + lane*16, imm offsets {0,1024,2048,3072}.
// W4T block: [i][k] transpose, i*512+k.
__global__ void pack_weights(const float* __restrict__ sW1, const float* __restrict__ sW2,
                             const float* __restrict__ sW3, const float* __restrict__ sW4,
                             const float* __restrict__ tW1, const float* __restrict__ tW2,
                             const float* __restrict__ tW3, const float* __restrict__ tW4,
                             f16* __restrict__ dst) {
  int idx = blockIdx.x * 256 + threadIdx.x;  // 4608*256 == 2*WPACK_PER_NET
  int net = idx >= WPACK_PER_NET;
  int f = idx - net * WPACK_PER_NET;
  const float* W;
  int base;
  if (f < OFF_W2) {
    W = net ? tW1 : sW1; base = OFF_W1;
  } else if (f < OFF_W3) {
    W = net ? tW2 : sW2; base = OFF_W2;
  } else if (f < OFF_W4T) {
    W = net ? tW3 : sW3; base = OFF_W3;
  } else {
    int f4 = f - OFF_W4T;
    dst[idx] = (f16)((net ? tW4 : sW4)[(f4 & 511) * 64 + (f4 >> 9)]);
    return;
  }
  int fl = f - base;
  int j = fl & 7, ln = (fl >> 3) & 63, nt = (fl >> 9) & 3, w = (fl >> 11) & 7,
      kk = fl >> 14;
  dst[idx] =
      (f16)W[(kk * 32 + (ln >> 4) * 8 + j) * 512 + w * 64 + nt * 16 + (ln & 15)];
}

// A-fragment order index for activation element (m,k).
__device__ __forceinline__ int aidx(int m, int k) {
  return (((k >> 5) * 4 + (m >> 4)) * 64 + (m & 15) + ((k >> 3) & 3) * 16) * 8 + (k & 7);
}

// tanh(x) = 1 - 2/(exp(2x)+1); 6 VALU inst, correct saturation.
__device__ __forceinline__ float fast_tanh(float x) {
  float e = __expf(x + x);
  return fmaf(-2.0f, __builtin_amdgcn_rcpf(e + 1.0f), 1.0f);
}

// One MLP layer: Hout(64x512) = tanh(Asrc(64xK) @ W + bias).
// wlb = wave's byte base into the layer's packed block. Depth-1 double
// buffer; per-slice address step is +32768 bytes; 4 loads/slice via
// immediate offsets. a-frags loaded one per mt (min liveness).
template <int NS>
__device__ __forceinline__ void mlp_layer(const char* __restrict__ wlb,
                                          const float* __restrict__ bias,
                                          const f16* Asrc, f16* Hout,
                                          int wave, int lane, int sbase) {
  f32x4 acc[4][4];
#pragma unroll
  for (int nt = 0; nt < 4; nt++) {
    float bv = bias[wave * 64 + nt * 16 + (lane & 15)];
#pragma unroll
    for (int mt = 0; mt < 4; mt++) acc[mt][nt] = f32x4{bv, bv, bv, bv};
  }
  f16x8 bb[2][4];
#pragma unroll
  for (int nt = 0; nt < 4; nt++) bb[0][nt] = *(const f16x8*)(wlb + nt * 1024);
#pragma unroll
  for (int kk = 0; kk < NS; kk++) {
    if (kk + 1 < NS) {
      const char* q = wlb + (kk + 1) * 32768;
#pragma unroll
      for (int nt = 0; nt < 4; nt++)
        bb[(kk + 1) & 1][nt] = *(const f16x8*)(q + nt * 1024);
    }
    const f16* ab = Asrc + kk * 2048 + lane * 8;
#pragma unroll
    for (int mt = 0; mt < 4; mt++) {
      f16x8 a = *(const f16x8*)(ab + mt * 512);
#pragma unroll
      for (int nt = 0; nt < 4; nt++)
        acc[mt][nt] = __builtin_amdgcn_mfma_f32_16x16x32_f16(a, bb[kk & 1][nt],
                                                             acc[mt][nt], 0, 0, 0);
    }
  }
  lds_barrier();  // all waves done reading Asrc (aliases Hout)
  // C/D (m89/m91): col=wave*64+nt*16+(lane&15), row=mt*16+(lane>>4)*4+r.
  // Scatter = sbase(lane) + const(mt,nt,r)  [verified R4].
  f16* hb = Hout + sbase;
#pragma unroll
  for (int mt = 0; mt < 4; mt++)
#pragma unroll
    for (int nt = 0; nt < 4; nt++)
#pragma unroll
      for (int r = 0; r < 4; r++)
        hb[(nt >> 1) * 2048 + mt * 512 + (nt & 1) * 256 + r * 8] =
            (f16)fast_tanh(acc[mt][nt][r]);
  lds_barrier();
}

__global__ __launch_bounds__(512, 4) void decoder_main(
    const float* __restrict__ x, const float* __restrict__ koop,
    const f16* __restrict__ wpack,
    const float* __restrict__ sb1, const float* __restrict__ sb2,
    const float* __restrict__ sb3, const float* __restrict__ sb4,
    const float* __restrict__ tb1, const float* __restrict__ tb2,
    const float* __restrict__ tb3, const float* __restrict__ tb4,
    float* __restrict__ out) {
  __shared__ __align__(16) f16 ZA[4096];   // z tile, A-frag order (8 KB)
  __shared__ __align__(16) f16 HA[32768];  // activations (64 KB)
  __shared__ float redBuf[2][64];
  // 72.5 KB -> 2 WG/CU

  const int b = blockIdx.x;
  const int t = threadIdx.x;
  const int wave = t >> 6, lane = t & 63;
  const int sbase =
      wave * 4096 + (lane >> 4) * 32 + ((lane & 15) >> 3) * 128 + (lane & 7);
  // Wave's byte base within any layer block.
  const char* wbb = (const char*)wpack + wave * 4096 + lane * 16;

  // Stage z = koopman[b]^T as f16 A-fragments.
  const float* kb = koop + b * 4096;
#pragma unroll
  for (int i = 0; i < 8; i++) {
    int flat = t + 512 * i;
    ZA[aidx(flat & 63, flat >> 6)] = (f16)kb[flat];
  }
  lds_barrier();

  for (int net = 0; net < 2; net++) {
    const size_t nb = (size_t)net * (WPACK_PER_NET * 2);
    const float* b1 = net ? tb1 : sb1;
    const float* b2 = net ? tb2 : sb2;
    const float* b3 = net ? tb3 : sb3;
    const float* b4 = net ? tb4 : sb4;
    mlp_layer<2>(wbb + nb + OFF_W1 * 2, b1, ZA, HA, wave, lane, sbase);
    mlp_layer<16>(wbb + nb + OFF_W2 * 2, b2, HA, HA, wave, lane, sbase);
    mlp_layer<16>(wbb + nb + OFF_W3 * 2, b3, HA, HA, wave, lane, sbase);

    // Diagonal epilogue: ds[i] = H3[i,:] . W4T[i,:] + b4[i].
    const f16* w4t = wpack + net * WPACK_PER_NET + OFF_W4T;
    int i = t >> 3, sub = t & 7;
    float p = 0.f;
#pragma unroll
    for (int q = 0; q < 8; q++) {
      int k0 = sub * 64 + q * 8;
      f16x8 hv = *(const f16x8*)&HA[aidx(i, k0)];
      f16x8 wv = *(const f16x8*)&w4t[i * 512 + k0];
#pragma unroll
      for (int j = 0; j < 8; j++) p += (float)hv[j] * (float)wv[j];
    }
    p += __shfl_down(p, 4, 8);
    p += __shfl_down(p, 2, 8);
    p += __shfl_down(p, 1, 8);
    if (sub == 0) redBuf[net][i] = p + b4[i];
    lds_barrier();
  }

  if (t < 64) {
    out[b * 64 + t] = (x[b * 64 + t] - redBuf[1][t]) * __expf(-redBuf[0][t]);
  }
}

// ---------------- DIRECT fallback (no workspace) — R4 code ---------------
__device__ __forceinline__ void load_b_direct(const float* __restrict__ Wraw,
                                              int kk, int wave, int lane,
                                              f16x8* bdst) {
  int n0 = wave * 64 + (lane & 15);
  int kb = kk * 32 + (lane >> 4) * 8;
#pragma unroll
  for (int nt = 0; nt < 4; nt++) {
    f16x8 v;
#pragma unroll
    for (int j = 0; j < 8; j++) v[j] = (f16)Wraw[(kb + j) * 512 + n0 + nt * 16];
    bdst[nt] = v;
  }
}

template <int NS>
__device__ __forceinline__ void mlp_layer_direct(
    const float* __restrict__ Wraw, const float* __restrict__ bias,
    const f16* Asrc, f16* Hout, int wave, int lane, int sbase) {
  f32x4 acc[4][4];
#pragma unroll
  for (int nt = 0; nt < 4; nt++) {
    float bv = bias[wave * 64 + nt * 16 + (lane & 15)];
#pragma unroll
    for (int mt = 0; mt < 4; mt++) acc[mt][nt] = f32x4{bv, bv, bv, bv};
  }
  f16x8 bb[2][4];
  load_b_direct(Wraw, 0, wave, lane, bb[0]);
#pragma unroll
  for (int kk = 0; kk < NS; kk++) {
    if (kk + 1 < NS) load_b_direct(Wraw, kk + 1, wave, lane, bb[(kk + 1) & 1]);
    const f16* ab = Asrc + kk * 2048 + lane * 8;
#pragma unroll
    for (int mt = 0; mt < 4; mt++) {
      f16x8 a = *(const f16x8*)(ab + mt * 512);
#pragma unroll
      for (int nt = 0; nt < 4; nt++)
        acc[mt][nt] = __builtin_amdgcn_mfma_f32_16x16x32_f16(a, bb[kk & 1][nt],
                                                             acc[mt][nt], 0, 0, 0);
    }
  }
  __syncthreads();
  f16* hb = Hout + sbase;
#pragma unroll
  for (int mt = 0; mt < 4; mt++)
#pragma unroll
    for (int nt = 0; nt < 4; nt++)
#pragma unroll
      for (int r = 0; r < 4; r++)
        hb[(nt >> 1) * 2048 + mt * 512 + (nt & 1) * 256 + r * 8] =
            (f16)fast_tanh(acc[mt][nt][r]);
  __syncthreads();
}

__global__ __launch_bounds__(512, 4) void decoder_direct(
    const float* __restrict__ x, const float* __restrict__ koop,
    const float* __restrict__ sW1, const float* __restrict__ sW2,
    const float* __restrict__ sW3, const float* __restrict__ sW4,
    const float* __restrict__ tW1, const float* __restrict__ tW2,
    const float* __restrict__ tW3, const float* __restrict__ tW4,
    const float* __restrict__ sb1, const float* __restrict__ sb2,
    const float* __restrict__ sb3, const float* __restrict__ sb4,
    const float* __restrict__ tb1, const float* __restrict__ tb2,
    const float* __restrict__ tb3, const float* __restrict__ tb4,
    float* __restrict__ out) {
  __shared__ __align__(16) f16 ZA[4096];
  __shared__ __align__(16) f16 HA[32768];
  __shared__ float redBuf[2][64];
  const int b = blockIdx.x;
  const int t = threadIdx.x;
  const int wave = t >> 6, lane = t & 63;
  const int sbase =
      wave * 4096 + (lane >> 4) * 32 + ((lane & 15) >> 3) * 128 + (lane & 7);
  const float* kb = koop + b * 4096;
#pragma unroll
  for (int i = 0; i < 8; i++) {
    int flat = t + 512 * i;
    ZA[aidx(flat & 63, flat >> 6)] = (f16)kb[flat];
  }
  __syncthreads();
  for (int net = 0; net < 2; net++) {
    const float* W1 = net ? tW1 : sW1;
    const float* W2 = net ? tW2 : sW2;
    const float* W3 = net ? tW3 : sW3;
    const float* W4 = net ? tW4 : sW4;
    const float* b1 = net ? tb1 : sb1;
    const float* b2 = net ? tb2 : sb2;
    const float* b3 = net ? tb3 : sb3;
    const float* b4 = net ? tb4 : sb4;
    mlp_layer_direct<2>(W1, b1, ZA, HA, wave, lane, sbase);
    mlp_layer_direct<16>(W2, b2, HA, HA, wave, lane, sbase);
    mlp_layer_direct<16>(W3, b3, HA, HA, wave, lane, sbase);
    int i = t >> 3, sub = t & 7;
    float p = 0.f;
#pragma unroll
    for (int q = 0; q < 8; q++) {
      int k0 = sub * 64 + q * 8;
      f16x8 hv = *(const f16x8*)&HA[aidx(i, k0)];
#pragma unroll
      for (int j = 0; j < 8; j++) p += (float)hv[j] * W4[(k0 + j) * 64 + i];
    }
    p += __shfl_down(p, 4, 8);
    p += __shfl_down(p, 2, 8);
    p += __shfl_down(p, 1, 8);
    if (sub == 0) redBuf[net][i] = p + b4[i];
    __syncthreads();
  }
  if (t < 64) {
    out[b * 64 + t] = (x[b * 64 + t] - redBuf[1][t]) * __expf(-redBuf[0][t]);
  }
}

extern "C" void kernel_launch(void* const* d_in, const int* in_sizes, int n_in,
                              void* d_out, int out_size, void* d_ws, size_t ws_size,
                              hipStream_t stream) {
  const float* x    = (const float*)d_in[0];
  const float* koop = (const float*)d_in[1];
  const float* sW1 = (const float*)d_in[2];  const float* sb1 = (const float*)d_in[3];
  const float* sW2 = (const float*)d_in[4];  const float* sb2 = (const float*)d_in[5];
  const float* sW3 = (const float*)d_in[6];  const float* sb3 = (const float*)d_in[7];
  const float* sW4 = (const float*)d_in[8];  const float* sb4 = (const float*)d_in[9];
  const float* tW1 = (const float*)d_in[10]; const float* tb1 = (const float*)d_in[11];
  const float* tW2 = (const float*)d_in[12]; const float* tb2 = (const float*)d_in[13];
  const float* tW3 = (const float*)d_in[14]; const float* tb3 = (const float*)d_in[15];
  const float* tW4 = (const float*)d_in[16]; const float* tb4 = (const float*)d_in[17];
  float* out = (float*)d_out;

  // Launch-invariant branch (ws_size constant across calls) -> graph-safe.
  // NEVER write past ws_size (R1 lesson).
  if (ws_size >= (size_t)WPACK_BYTES) {
    f16* wpack = (f16*)d_ws;
    pack_weights<<<4608, 256, 0, stream>>>(sW1, sW2, sW3, sW4, tW1, tW2, tW3, tW4,
                                           wpack);
    decoder_main<<<2048, 512, 0, stream>>>(x, koop, wpack,
                                           sb1, sb2, sb3, sb4,
                                           tb1, tb2, tb3, tb4, out);
  } else {
    decoder_direct<<<2048, 512, 0, stream>>>(
        x, koop, sW1, sW2, sW3, sW4, tW1, tW2, tW3, tW4,
        sb1, sb2, sb3, sb4, tb1, tb2, tb3, tb4, out);
  }
}